// Round 3
// baseline (75.258 us; speedup 1.0000x reference)
//
#include <hip/hip_runtime.h>

// Geometric product in Cl(3,0), blades short-lex ordered:
// idx: 0=1, 1=e1, 2=e2, 3=e3, 4=e12, 5=e13, 6=e23, 7=e123
// Hardcoded 64-term signed product table (METRIC=[1,1,1] fixed in setup_inputs).
// Memory-bound streaming kernel: 1 thread = 1 multivector pair (32B each).
// Round 3: non-temporal stores via clang ext_vector type (HIP_vector_type
// float4 is rejected by __builtin_nontemporal_store).

typedef float v4f __attribute__((ext_vector_type(4)));

__global__ __launch_bounds__(256) void clifford_gp_kernel(
    const v4f* __restrict__ a4, const v4f* __restrict__ b4,
    v4f* __restrict__ o4, int n_mv)
{
    int t = blockIdx.x * blockDim.x + threadIdx.x;
    if (t >= n_mv) return;

    v4f alo = a4[2 * t], ahi = a4[2 * t + 1];
    v4f blo = b4[2 * t], bhi = b4[2 * t + 1];

    float a0 = alo.x, a1 = alo.y, a2 = alo.z, a3 = alo.w;
    float A4 = ahi.x, a5 = ahi.y, a6 = ahi.z, a7 = ahi.w;
    float b0 = blo.x, b1 = blo.y, b2 = blo.z, b3 = blo.w;
    float B4 = bhi.x, b5 = bhi.y, b6 = bhi.z, b7 = bhi.w;

    v4f olo, ohi;
    // scalar
    olo.x = a0*b0 + a1*b1 + a2*b2 + a3*b3 - A4*B4 - a5*b5 - a6*b6 - a7*b7;
    // e1
    olo.y = a0*b1 + a1*b0 - a2*B4 + A4*b2 - a3*b5 + a5*b3 - a6*b7 - a7*b6;
    // e2
    olo.z = a0*b2 + a2*b0 + a1*B4 - A4*b1 - a3*b6 + a6*b3 + a5*b7 + a7*b5;
    // e3
    olo.w = a0*b3 + a3*b0 + a1*b5 - a5*b1 + a2*b6 - a6*b2 - A4*b7 - a7*B4;
    // e12
    ohi.x = a0*B4 + A4*b0 + a1*b2 - a2*b1 + a3*b7 + a7*b3 - a5*b6 + a6*b5;
    // e13
    ohi.y = a0*b5 + a5*b0 + a1*b3 - a3*b1 - a2*b7 - a7*b2 + A4*b6 - a6*B4;
    // e23
    ohi.z = a0*b6 + a6*b0 + a2*b3 - a3*b2 + a1*b7 + a7*b1 - A4*b5 + a5*B4;
    // e123
    ohi.w = a0*b7 + a7*b0 + a1*b6 + a6*b1 - a2*b5 - a5*b2 + a3*B4 + A4*b3;

    __builtin_nontemporal_store(olo, &o4[2 * t]);
    __builtin_nontemporal_store(ohi, &o4[2 * t + 1]);
}

extern "C" void kernel_launch(void* const* d_in, const int* in_sizes, int n_in,
                              void* d_out, int out_size, void* d_ws, size_t ws_size,
                              hipStream_t stream) {
    const v4f* a = (const v4f*)d_in[0];
    const v4f* b = (const v4f*)d_in[1];
    v4f* out = (v4f*)d_out;
    int n_mv = in_sizes[0] / 8;  // 65536*64 = 4,194,304 multivectors
    int block = 256;
    int grid = (n_mv + block - 1) / block;
    clifford_gp_kernel<<<grid, block, 0, stream>>>(a, b, out, n_mv);
}

// Round 4
// 72.913 us; speedup vs baseline: 1.0322x; 1.0322x over previous
//
#include <hip/hip_runtime.h>

// Geometric product in Cl(3,0), blades short-lex ordered:
// idx: 0=1, 1=e1, 2=e2, 3=e3, 4=e12, 5=e13, 6=e23, 7=e123
// Hardcoded 64-term signed table (METRIC=[1,1,1] fixed in setup_inputs).
//
// Round 4: lane-pair layout for perfect stride-1 coalescing.
// Thread t loads flat float4 chunk t of a and b (16B/lane, stride-1),
// swaps the partner half with lane t^1 via __shfl_xor, computes the full
// product, and stores its own 16B output chunk stride-1.
// (Round-3 lesson: nontemporal stores bypass L3 write-back -> +55% write
// traffic and +40% time. Reverted.)

typedef float v4f __attribute__((ext_vector_type(4)));

__global__ __launch_bounds__(256) void clifford_gp_kernel(
    const v4f* __restrict__ a4, const v4f* __restrict__ b4,
    v4f* __restrict__ o4, int n_chunks)
{
    int t = blockIdx.x * blockDim.x + threadIdx.x;
    if (t >= n_chunks) return;

    v4f ma = a4[t];
    v4f mb = b4[t];

    // Partner lane (t^1 == lane^1) holds the other 16B half of this mv.
    v4f oa, ob;
    oa.x = __shfl_xor(ma.x, 1); oa.y = __shfl_xor(ma.y, 1);
    oa.z = __shfl_xor(ma.z, 1); oa.w = __shfl_xor(ma.w, 1);
    ob.x = __shfl_xor(mb.x, 1); ob.y = __shfl_xor(mb.y, 1);
    ob.z = __shfl_xor(mb.z, 1); ob.w = __shfl_xor(mb.w, 1);

    bool lo = (t & 1) == 0;  // even chunk = blades 0-3, odd = blades 4-7
    float a0 = lo ? ma.x : oa.x, a1 = lo ? ma.y : oa.y;
    float a2 = lo ? ma.z : oa.z, a3 = lo ? ma.w : oa.w;
    float A4 = lo ? oa.x : ma.x, a5 = lo ? oa.y : ma.y;
    float a6 = lo ? oa.z : ma.z, a7 = lo ? oa.w : ma.w;
    float b0 = lo ? mb.x : ob.x, b1 = lo ? mb.y : ob.y;
    float b2 = lo ? mb.z : ob.z, b3 = lo ? mb.w : ob.w;
    float B4 = lo ? ob.x : mb.x, b5 = lo ? ob.y : mb.y;
    float b6 = lo ? ob.z : mb.z, b7 = lo ? ob.w : mb.w;

    v4f olo, ohi;
    // scalar
    olo.x = a0*b0 + a1*b1 + a2*b2 + a3*b3 - A4*B4 - a5*b5 - a6*b6 - a7*b7;
    // e1
    olo.y = a0*b1 + a1*b0 - a2*B4 + A4*b2 - a3*b5 + a5*b3 - a6*b7 - a7*b6;
    // e2
    olo.z = a0*b2 + a2*b0 + a1*B4 - A4*b1 - a3*b6 + a6*b3 + a5*b7 + a7*b5;
    // e3
    olo.w = a0*b3 + a3*b0 + a1*b5 - a5*b1 + a2*b6 - a6*b2 - A4*b7 - a7*B4;
    // e12
    ohi.x = a0*B4 + A4*b0 + a1*b2 - a2*b1 + a3*b7 + a7*b3 - a5*b6 + a6*b5;
    // e13
    ohi.y = a0*b5 + a5*b0 + a1*b3 - a3*b1 - a2*b7 - a7*b2 + A4*b6 - a6*B4;
    // e23
    ohi.z = a0*b6 + a6*b0 + a2*b3 - a3*b2 + a1*b7 + a7*b1 - A4*b5 + a5*B4;
    // e123
    ohi.w = a0*b7 + a7*b0 + a1*b6 + a6*b1 - a2*b5 - a5*b2 + a3*B4 + A4*b3;

    v4f r;
    r.x = lo ? olo.x : ohi.x;
    r.y = lo ? olo.y : ohi.y;
    r.z = lo ? olo.z : ohi.z;
    r.w = lo ? olo.w : ohi.w;
    o4[t] = r;
}

extern "C" void kernel_launch(void* const* d_in, const int* in_sizes, int n_in,
                              void* d_out, int out_size, void* d_ws, size_t ws_size,
                              hipStream_t stream) {
    const v4f* a = (const v4f*)d_in[0];
    const v4f* b = (const v4f*)d_in[1];
    v4f* out = (v4f*)d_out;
    int n_chunks = in_sizes[0] / 4;  // 65536*64*8/4 = 8,388,608 float4 chunks
    int block = 256;
    int grid = (n_chunks + block - 1) / block;
    clifford_gp_kernel<<<grid, block, 0, stream>>>(a, b, out, n_chunks);
}